// Round 15
// baseline (2834.219 us; speedup 1.0000x reference)
//
#include <hip/hip_runtime.h>
#include <hip/hip_bf16.h>
#include <cstdint>
#include <cstddef>

#define HID 512
#define N_INT 131072
#define N_INIT 32768
#define WT1 ((size_t)HID * HID)

typedef __attribute__((ext_vector_type(8))) short short8_t;
typedef __attribute__((ext_vector_type(4))) short short4_t;
typedef __attribute__((ext_vector_type(4))) float floatx4;

__device__ __forceinline__ float bf2f(unsigned short u) {
  return __uint_as_float(((unsigned)u) << 16);
}
__device__ __forceinline__ unsigned short f2bf_rne(float x) {
  unsigned u = __float_as_uint(x);
  unsigned r = u + 0x7FFF + ((u >> 16) & 1);
  return (unsigned short)(r >> 16);
}
__device__ __forceinline__ void st_split(unsigned short* hi, unsigned short* lo,
                                         size_t off, float x) {
  unsigned short h = f2bf_rne(x);
  hi[off] = h;
  lo[off] = f2bf_rne(x - bf2f(h));
}

// LDS activation plane layout: [16 rows][1024 ushorts: hi 0..511 | lo 512..1023],
// 16B slot index XOR-swizzled with (row&7). aoff preserves uscol&7, so any
// write/read within one 8-ushort slot stays contiguous.
__device__ __forceinline__ int aoff(int row, int uscol) {
  return (row << 10) + ((((uscol >> 3) ^ (row & 7)) << 3) | (uscol & 7));
}

// ---------------------------------------------------------------------------
// W split + pack into B-fraglet layout (same as prior verified rounds):
//   fraglet (n>>4, k>>5); lane = ((k>>3)&3)*16 + (n&15); elem = k&7.
// ---------------------------------------------------------------------------
__global__ __launch_bounds__(512) void wsplit(
    const float* __restrict__ W,
    unsigned short* __restrict__ WfH, unsigned short* __restrict__ WfL)
{
  int n = blockIdx.x;
  int k = threadIdx.x;
  float w = W[(size_t)k * HID + n];
  size_t o = ((((size_t)(n >> 4) * 16 + (k >> 5)) * 64
               + ((k >> 3) & 3) * 16 + (n & 15)) << 3) + (k & 7);
  st_split(WfH, WfL, o, w);
}

// ---------------------------------------------------------------------------
// Fully fused MLP pass, swapped-operand MFMA + register-disciplined pipeline.
// Two-phase NAMED B double-buffer (bhA/blA <-> bhB/blB), 2 k-tiles per loop
// iteration -> no runtime-indexed register arrays (rule-20-safe under any
// unroll decision). B addressed via shared 32-bit offsets off the SGPR weight
// base (4 regs). A addresses parity-decomposed to 2 scalars (eE0/eO0).
// Estimated demand ~205 unified regs < 256 cap (2 waves/EU) -> no spill.
// mfma(W_frag, Act_frag): output lane&15 = m-row, reg j = consecutive n.
// Product terms & order identical to rounds 2-14 -> bit-identical numerics.
// Block = 16 rows x 512 cols, 512 thr (8 waves, each owns a 64-col slice).
// ---------------------------------------------------------------------------
template <int NS>
__global__ __launch_bounds__(512, 2) void fused_mlp(
    const float* __restrict__ xt,
    const float* __restrict__ W0, const float* __restrict__ b0,
    const unsigned short* __restrict__ Wf,   // 6 planes: L1H,L1L,L2H,L2L,L3H,L3L
    const float* __restrict__ b1, const float* __restrict__ b2,
    const float* __restrict__ b3,
    const float* __restrict__ W4, const float* __restrict__ b4,
    const float* __restrict__ cc,            // c (interior), unused for init
    const float* __restrict__ t0,            // f (interior) or g (init)
    const float* __restrict__ t1,            // unused or gd (init)
    float* __restrict__ out, float scale)
{
  __shared__ unsigned short Ald[NS][16][1024];  // NS=5 -> 160 KiB, NS=2 -> 64 KiB

  const int tid = threadIdx.x;
  const long rowbase = (long)blockIdx.x * 16;

  // ---- layer 0: closed-form tangents straight into LDS ----
  {
    const int row = tid & 15;
    const int cg = tid >> 4;  // 0..31, 16 cols each
    const long gr = rowbase + row;
    const float x = xt[gr * 2 + 0];
    const float tv = xt[gr * 2 + 1];
#pragma unroll
    for (int sc = 0; sc < 2; ++sc) {
      const int j0 = cg * 16 + sc * 8;
      short8_t h[NS], l[NS];
#pragma unroll
      for (int jj = 0; jj < 8; ++jj) {
        const float wx = W0[j0 + jj];
        const float wt = W0[HID + j0 + jj];
        const float a = fmaf(x, wx, fmaf(tv, wt, b0[j0 + jj]));
        const float y = tanhf(a);
        const float d = 1.f - y * y;
        const float vals[5] = {y, d * wt, -2.f * y * d * wt * wt,
                               d * wx, -2.f * y * d * wx * wx};
#pragma unroll
        for (int p = 0; p < NS; ++p) {
          const unsigned short hv = f2bf_rne(vals[p]);
          h[p][jj] = (short)hv;
          l[p][jj] = (short)f2bf_rne(vals[p] - bf2f(hv));
        }
      }
#pragma unroll
      for (int p = 0; p < NS; ++p) {
        *(short8_t*)&Ald[p][0][aoff(row, j0)] = h[p];
        *(short8_t*)&Ald[p][0][aoff(row, 512 + j0)] = l[p];
      }
    }
  }
  __syncthreads();

  // ---- 3 hidden GEMM layers ----
  const int lane = tid & 63;
  const int wv = tid >> 6;        // 0..7: 64-col slice
  const int row = lane & 15;      // operand row (m for act, n for W)
  const int kq = lane >> 4;       // k-quarter
  const int rx = row & 7;
  const unsigned short* __restrict__ Aflat = &Ald[0][0][0];

  // Parity-decomposed A-fragment ushort indices:
  // slot(t) = (kq^rx01) | (((t&1)^rx2)<<2) | ((t>>1)<<3); idx = slot*8.
  const int rxl = rx & 3, rx2 = (rx >> 2) & 1;
  const unsigned eE0 = ((unsigned)row << 10)
                     + ((unsigned)((kq ^ rxl) | (rx2 << 2)) << 3);
  const unsigned eO0 = ((unsigned)row << 10)
                     + ((unsigned)((kq ^ rxl) | ((1 ^ rx2) << 2)) << 3);

  for (int L = 0; L < 3; ++L) {
    const unsigned short* __restrict__ WH = Wf + (size_t)L * 2 * WT1;
    const unsigned short* __restrict__ WL2 = WH + WT1;

    unsigned bOff[4];
#pragma unroll
    for (int cf = 0; cf < 4; ++cf)
      bOff[cf] = ((unsigned)(wv * 4 + cf) << 13) + ((unsigned)lane << 3);

    floatx4 acc[NS][4];
#pragma unroll
    for (int s = 0; s < NS; ++s)
#pragma unroll
      for (int cf = 0; cf < 4; ++cf)
#pragma unroll
        for (int e = 0; e < 4; ++e) acc[s][cf][e] = 0.f;

    // Named two-phase B double buffer; prologue loads t=0 into A-phase regs.
    short8_t bhA[4], blA[4], bhB[4], blB[4];
#pragma unroll
    for (int cf = 0; cf < 4; ++cf) {
      bhA[cf] = *(const short8_t*)(WH + bOff[cf]);
      blA[cf] = *(const short8_t*)(WL2 + bOff[cf]);
    }

#pragma unroll
    for (int tp = 0; tp < 8; ++tp) {
      const unsigned ko = (unsigned)tp * 64u;
      // prefetch B for odd tile t=2tp+1 into B-phase regs
#pragma unroll
      for (int cf = 0; cf < 4; ++cf) {
        const unsigned o = bOff[cf] + (unsigned)((2 * tp + 1) << 9);
        bhB[cf] = *(const short8_t*)(WH + o);
        blB[cf] = *(const short8_t*)(WL2 + o);
      }
      {  // even tile t=2tp: A frags via eE0, B from A-phase regs
        short8_t ah[NS], al[NS];
#pragma unroll
        for (int s = 0; s < NS; ++s) {
          const unsigned e = eE0 + (unsigned)s * 16384u + ko;
          ah[s] = *(const short8_t*)&Aflat[e];
          al[s] = *(const short8_t*)&Aflat[e + 512];
        }
        __builtin_amdgcn_s_setprio(1);
#pragma unroll
        for (int s = 0; s < NS; ++s)
#pragma unroll
          for (int cf = 0; cf < 4; ++cf) {
            acc[s][cf] = __builtin_amdgcn_mfma_f32_16x16x32_bf16(bhA[cf], ah[s], acc[s][cf], 0, 0, 0);
            acc[s][cf] = __builtin_amdgcn_mfma_f32_16x16x32_bf16(blA[cf], ah[s], acc[s][cf], 0, 0, 0);
            acc[s][cf] = __builtin_amdgcn_mfma_f32_16x16x32_bf16(bhA[cf], al[s], acc[s][cf], 0, 0, 0);
          }
        __builtin_amdgcn_s_setprio(0);
      }
      if (tp < 7) {
        // prefetch B for next even tile t=2tp+2 into A-phase regs
#pragma unroll
        for (int cf = 0; cf < 4; ++cf) {
          const unsigned o = bOff[cf] + (unsigned)((2 * tp + 2) << 9);
          bhA[cf] = *(const short8_t*)(WH + o);
          blA[cf] = *(const short8_t*)(WL2 + o);
        }
      }
      {  // odd tile t=2tp+1: A frags via eO0, B from B-phase regs
        short8_t ah[NS], al[NS];
#pragma unroll
        for (int s = 0; s < NS; ++s) {
          const unsigned e = eO0 + (unsigned)s * 16384u + ko;
          ah[s] = *(const short8_t*)&Aflat[e];
          al[s] = *(const short8_t*)&Aflat[e + 512];
        }
        __builtin_amdgcn_s_setprio(1);
#pragma unroll
        for (int s = 0; s < NS; ++s)
#pragma unroll
          for (int cf = 0; cf < 4; ++cf) {
            acc[s][cf] = __builtin_amdgcn_mfma_f32_16x16x32_bf16(bhB[cf], ah[s], acc[s][cf], 0, 0, 0);
            acc[s][cf] = __builtin_amdgcn_mfma_f32_16x16x32_bf16(blB[cf], ah[s], acc[s][cf], 0, 0, 0);
            acc[s][cf] = __builtin_amdgcn_mfma_f32_16x16x32_bf16(bhB[cf], al[s], acc[s][cf], 0, 0, 0);
          }
        __builtin_amdgcn_s_setprio(0);
      }
    }
    __syncthreads();  // all waves done reading this layer's activations

    // In swapped layout: this lane's 16 outputs are for m-row = `row`,
    // n = wv*64 + cf*16 + kq*4 + j  (4 consecutive n per cf).
    if (L < 2) {
      const float* __restrict__ bias = (L == 0) ? b1 : b2;
#pragma unroll
      for (int cf = 0; cf < 4; ++cf) {
        const int n = (wv << 6) + (cf << 4) + (kq << 2);
        const float4 bv4 = *(const float4*)(bias + n);
        const float bvv[4] = {bv4.x, bv4.y, bv4.z, bv4.w};
        short4_t h[NS], l[NS];
#pragma unroll
        for (int j = 0; j < 4; ++j) {
          const float a0 = acc[0][cf][j] + bvv[j];
          const float e = __expf(2.f * a0);
          const float y = 1.f - __fdividef(2.f, e + 1.f);
          const float d = 1.f - y * y;
          const float a1 = acc[1][cf][j];
          const float o1 = d * a1;
          float vals[5];
          vals[0] = y;
          vals[1] = o1;
          if (NS == 5) {
            const float a2 = acc[2][cf][j];
            const float a3 = acc[3][cf][j];
            const float a4 = acc[4][cf][j];
            vals[2] = fmaf(-2.f * y * a1, o1, d * a2);
            vals[3] = d * a3;
            vals[4] = fmaf(-2.f * y * vals[3], a3, d * a4);
          }
#pragma unroll
          for (int p = 0; p < NS; ++p) {
            const unsigned short hv = f2bf_rne(vals[p]);
            h[p][j] = (short)hv;
            l[p][j] = (short)f2bf_rne(vals[p] - bf2f(hv));
          }
        }
#pragma unroll
        for (int p = 0; p < NS; ++p) {
          *(short4_t*)&Ald[p][0][aoff(row, n)] = h[p];
          *(short4_t*)&Ald[p][0][aoff(row, 512 + n)] = l[p];
        }
      }
      __syncthreads();
    } else {
      // ---- final layer: coupling + 512->1 dot + loss ----
      float s0 = 0.f, s1 = 0.f;
#pragma unroll
      for (int cf = 0; cf < 4; ++cf) {
        const int n = (wv << 6) + (cf << 4) + (kq << 2);
        const float4 bv4 = *(const float4*)(b3 + n);
        const float4 w44 = *(const float4*)(W4 + n);
        const float bvv[4] = {bv4.x, bv4.y, bv4.z, bv4.w};
        const float wvv[4] = {w44.x, w44.y, w44.z, w44.w};
#pragma unroll
        for (int j = 0; j < 4; ++j) {
          const float a0 = acc[0][cf][j] + bvv[j];
          const float e = __expf(2.f * a0);
          const float y = 1.f - __fdividef(2.f, e + 1.f);
          const float d = 1.f - y * y;
          const float a1 = acc[1][cf][j];
          const float o1 = d * a1;
          if (NS == 5) {
            const float a2 = acc[2][cf][j];
            const float a3 = acc[3][cf][j];
            const float a4 = acc[4][cf][j];
            const float o2 = fmaf(-2.f * y * a1, o1, d * a2);
            const float o3 = d * a3;
            const float o4 = fmaf(-2.f * y * o3, a3, d * a4);
            s0 = fmaf(o2, wvv[j], s0);   // u_tt partial for m-row `row`
            s1 = fmaf(o4, wvv[j], s1);   // u_xx partial
          } else {
            s0 = fmaf(y, wvv[j], s0);    // u partial
            s1 = fmaf(o1, wvv[j], s1);   // u_t partial
          }
        }
      }
      // reduce over the 4 kq-groups (lanes sharing m-row): flip bits 4,5
      s0 += __shfl_xor(s0, 16); s0 += __shfl_xor(s0, 32);
      s1 += __shfl_xor(s1, 16); s1 += __shfl_xor(s1, 32);
      // cross-wave reduce via LDS scratch (activations no longer needed)
      float* scr = (float*)&Ald[0][0][0];  // [2][8][16]
      if (lane < 16) {
        scr[(wv << 4) + lane] = s0;
        scr[128 + (wv << 4) + lane] = s1;
      }
      __syncthreads();
      if (tid < 16) {
        float q0 = 0.f, q1 = 0.f;
#pragma unroll
        for (int w = 0; w < 8; ++w) {
          q0 += scr[(w << 4) + tid];
          q1 += scr[128 + (w << 4) + tid];
        }
        if (NS == 5) {
          const float c0 = cc[0];
          const float pred = q0 - c0 * c0 * q1;
          const float r = pred - t0[rowbase + tid];
          float v = r * r;
#pragma unroll
          for (int off = 1; off < 16; off <<= 1) v += __shfl_xor(v, off);
          if (tid == 0) atomicAdd(out + 2, scale * v);
        } else {
          const float r0 = q0 + b4[0] - t0[rowbase + tid];
          const float r1 = q1 - t1[rowbase + tid];
          float v0 = r0 * r0, v1 = r1 * r1;
#pragma unroll
          for (int off = 1; off < 16; off <<= 1) {
            v0 += __shfl_xor(v0, off);
            v1 += __shfl_xor(v1, off);
          }
          if (tid == 0) {
            atomicAdd(out + 0, scale * v0);
            atomicAdd(out + 1, scale * v1);
          }
        }
      }
    }
  }
}

// ---------------------------------------------------------------------------
extern "C" void kernel_launch(void* const* d_in, const int* in_sizes, int n_in,
                              void* d_out, int out_size, void* d_ws, size_t ws_size,
                              hipStream_t stream)
{
  const float* xt_int  = (const float*)d_in[0];
  const float* f       = (const float*)d_in[1];
  const float* xt_init = (const float*)d_in[2];
  const float* g       = (const float*)d_in[3];
  const float* gd      = (const float*)d_in[4];
  const float* W0 = (const float*)d_in[5];
  const float* b0 = (const float*)d_in[6];
  const float* W1 = (const float*)d_in[7];
  const float* b1 = (const float*)d_in[8];
  const float* W2 = (const float*)d_in[9];
  const float* b2 = (const float*)d_in[10];
  const float* W3 = (const float*)d_in[11];
  const float* b3 = (const float*)d_in[12];
  const float* W4 = (const float*)d_in[13];
  const float* b4 = (const float*)d_in[14];
  const float* c  = (const float*)d_in[15];
  float* out = (float*)d_out;

  hipMemsetAsync(out, 0, 3 * sizeof(float), stream);

  unsigned short* Wt = (unsigned short*)d_ws;  // 6 planes = 3 MiB of ws

  wsplit<<<HID, HID, 0, stream>>>(W1, Wt + 0 * WT1, Wt + 1 * WT1);
  wsplit<<<HID, HID, 0, stream>>>(W2, Wt + 2 * WT1, Wt + 3 * WT1);
  wsplit<<<HID, HID, 0, stream>>>(W3, Wt + 4 * WT1, Wt + 5 * WT1);

  const float sc_f = 0.5f / (float)N_INT;
  const float sc_i = 0.5f / (float)N_INIT;

  fused_mlp<5><<<N_INT / 16, 512, 0, stream>>>(
      xt_int, W0, b0, Wt, b1, b2, b3, W4, b4, c, f, nullptr, out, sc_f);
  fused_mlp<2><<<N_INIT / 16, 512, 0, stream>>>(
      xt_init, W0, b0, Wt, b1, b2, b3, W4, b4, nullptr, g, gd, out, sc_i);
}

// Round 16
// 2538.585 us; speedup vs baseline: 1.1165x; 1.1165x over previous
//
#include <hip/hip_runtime.h>
#include <hip/hip_bf16.h>
#include <cstdint>
#include <cstddef>

#define HID 512
#define N_INT 131072
#define N_INIT 32768
#define WT1 ((size_t)HID * HID)

typedef __attribute__((ext_vector_type(8))) short short8_t;
typedef __attribute__((ext_vector_type(4))) short short4_t;
typedef __attribute__((ext_vector_type(4))) float floatx4;

__device__ __forceinline__ float bf2f(unsigned short u) {
  return __uint_as_float(((unsigned)u) << 16);
}
__device__ __forceinline__ unsigned short f2bf_rne(float x) {
  unsigned u = __float_as_uint(x);
  unsigned r = u + 0x7FFF + ((u >> 16) & 1);
  return (unsigned short)(r >> 16);
}
__device__ __forceinline__ void st_split(unsigned short* hi, unsigned short* lo,
                                         size_t off, float x) {
  unsigned short h = f2bf_rne(x);
  hi[off] = h;
  lo[off] = f2bf_rne(x - bf2f(h));
}

// Packed bf16 split of a float pair via HW cvt (RNE, same bits as f2bf_rne):
// hi = pack(bf16(a), bf16(b)); lo = pack(bf16(a - hi_a), bf16(b - hi_b)).
__device__ __forceinline__ void split_pair(float a, float b,
                                           unsigned& hi, unsigned& lo) {
  unsigned h;
  asm("v_cvt_pk_bf16_f32 %0, %1, %2" : "=v"(h) : "v"(a), "v"(b));
  const float ra = __uint_as_float(h << 16);
  const float rb = __uint_as_float(h & 0xffff0000u);
  unsigned l;
  asm("v_cvt_pk_bf16_f32 %0, %1, %2" : "=v"(l) : "v"(a - ra), "v"(b - rb));
  hi = h;
  lo = l;
}

// LDS activation plane layout: [16 rows][1024 ushorts: hi 0..511 | lo 512..1023],
// 16B slot index XOR-swizzled with (row&7). aoff preserves uscol&7, so any
// write/read within one 8-ushort slot stays contiguous.
__device__ __forceinline__ int aoff(int row, int uscol) {
  return (row << 10) + ((((uscol >> 3) ^ (row & 7)) << 3) | (uscol & 7));
}

// ---------------------------------------------------------------------------
// W split + pack into B-fraglet layout (same as prior verified rounds):
//   fraglet (n>>4, k>>5); lane = ((k>>3)&3)*16 + (n&15); elem = k&7.
// ---------------------------------------------------------------------------
__global__ __launch_bounds__(512) void wsplit(
    const float* __restrict__ W,
    unsigned short* __restrict__ WfH, unsigned short* __restrict__ WfL)
{
  int n = blockIdx.x;
  int k = threadIdx.x;
  float w = W[(size_t)k * HID + n];
  size_t o = ((((size_t)(n >> 4) * 16 + (k >> 5)) * 64
               + ((k >> 3) & 3) * 16 + (n & 15)) << 3) + (k & 7);
  st_split(WfH, WfL, o, w);
}

// ---------------------------------------------------------------------------
// Fully fused MLP pass, swapped-operand MFMA, TERM-MAJOR MFMA interleave.
// mfma(W_frag, Act_frag): output lane&15 = m-row, reg j = consecutive n.
// k-loop MFMA cluster is term-major (all accs get hh, then hl, then lh):
// same-acc reuse distance 20 (~388 cyc) >> MFMA latency -> no dep stalls.
// Per-acc accumulation order unchanged (hh,hl,lh) -> bit-identical numerics.
// Epilogues use v_cvt_pk_bf16_f32 (RNE, same bits) -> ~3x fewer VALU ops.
// Block = 16 rows x 512 cols, 512 thr (8 waves, each owns a 64-col slice).
// ---------------------------------------------------------------------------
template <int NS>
__global__ __launch_bounds__(512) void fused_mlp(
    const float* __restrict__ xt,
    const float* __restrict__ W0, const float* __restrict__ b0,
    const unsigned short* __restrict__ Wf,   // 6 planes: L1H,L1L,L2H,L2L,L3H,L3L
    const float* __restrict__ b1, const float* __restrict__ b2,
    const float* __restrict__ b3,
    const float* __restrict__ W4, const float* __restrict__ b4,
    const float* __restrict__ cc,            // c (interior), unused for init
    const float* __restrict__ t0,            // f (interior) or g (init)
    const float* __restrict__ t1,            // unused or gd (init)
    float* __restrict__ out, float scale)
{
  __shared__ unsigned short Ald[NS][16][1024];  // NS=5 -> 160 KiB, NS=2 -> 64 KiB

  const int tid = threadIdx.x;
  const long rowbase = (long)blockIdx.x * 16;

  // ---- layer 0: closed-form tangents straight into LDS ----
  {
    const int row = tid & 15;
    const int cg = tid >> 4;  // 0..31, 16 cols each
    const long gr = rowbase + row;
    const float x = xt[gr * 2 + 0];
    const float tv = xt[gr * 2 + 1];
#pragma unroll
    for (int sc = 0; sc < 2; ++sc) {
      const int j0 = cg * 16 + sc * 8;
      float v[NS][8];
#pragma unroll
      for (int jj = 0; jj < 8; ++jj) {
        const float wx = W0[j0 + jj];
        const float wt = W0[HID + j0 + jj];
        const float a = fmaf(x, wx, fmaf(tv, wt, b0[j0 + jj]));
        const float y = tanhf(a);
        const float d = 1.f - y * y;
        v[0][jj] = y;
        v[1][jj] = d * wt;
        if (NS == 5) {
          v[2][jj] = -2.f * y * d * wt * wt;
          v[3][jj] = d * wx;
          v[4][jj] = -2.f * y * d * wx * wx;
        }
      }
#pragma unroll
      for (int p = 0; p < NS; ++p) {
        union { unsigned u[4]; short8_t s8; } H, L;
#pragma unroll
        for (int q = 0; q < 4; ++q)
          split_pair(v[p][2 * q], v[p][2 * q + 1], H.u[q], L.u[q]);
        *(short8_t*)&Ald[p][0][aoff(row, j0)] = H.s8;
        *(short8_t*)&Ald[p][0][aoff(row, 512 + j0)] = L.s8;
      }
    }
  }
  __syncthreads();

  // ---- 3 hidden GEMM layers ----
  const int lane = tid & 63;
  const int wv = tid >> 6;        // 0..7: 64-col slice
  const int row = lane & 15;      // operand row (m for act, n for W)
  const int kq = lane >> 4;       // k-quarter
  const int rx = row & 7;
  const int rbase = row << 10;
  const unsigned short* __restrict__ Aflat = &Ald[0][0][0];

  for (int L = 0; L < 3; ++L) {
    const unsigned short* __restrict__ WH = Wf + (size_t)L * 2 * WT1;
    const unsigned short* __restrict__ WL2 = WH + WT1;

    floatx4 acc[NS][4];
#pragma unroll
    for (int s = 0; s < NS; ++s)
#pragma unroll
      for (int cf = 0; cf < 4; ++cf)
#pragma unroll
        for (int e = 0; e < 4; ++e) acc[s][cf][e] = 0.f;

#pragma unroll 4
    for (int t = 0; t < 16; ++t) {
      short8_t ah[NS], al[NS], bhv[4], blv[4];
#pragma unroll
      for (int s = 0; s < NS; ++s) {
        ah[s] = *(const short8_t*)&Aflat[(unsigned)s * 16384u + rbase + ((((t << 2) + kq) ^ rx) << 3)];
        al[s] = *(const short8_t*)&Aflat[(unsigned)s * 16384u + rbase + (((64 + (t << 2) + kq) ^ rx) << 3)];
      }
#pragma unroll
      for (int cf = 0; cf < 4; ++cf) {
        const size_t bo = (((size_t)((wv * 4 + cf) * 16 + t)) << 9) + (lane << 3);
        bhv[cf] = *(const short8_t*)(WH + bo);
        blv[cf] = *(const short8_t*)(WL2 + bo);
      }
      // term-major interleave: same-acc ops are 20 apart -> no dep stalls;
      // per-acc order stays hh, hl, lh -> bit-identical accumulation.
      __builtin_amdgcn_s_setprio(1);
#pragma unroll
      for (int s = 0; s < NS; ++s)
#pragma unroll
        for (int cf = 0; cf < 4; ++cf)
          acc[s][cf] = __builtin_amdgcn_mfma_f32_16x16x32_bf16(bhv[cf], ah[s], acc[s][cf], 0, 0, 0);
#pragma unroll
      for (int s = 0; s < NS; ++s)
#pragma unroll
        for (int cf = 0; cf < 4; ++cf)
          acc[s][cf] = __builtin_amdgcn_mfma_f32_16x16x32_bf16(blv[cf], ah[s], acc[s][cf], 0, 0, 0);
#pragma unroll
      for (int s = 0; s < NS; ++s)
#pragma unroll
        for (int cf = 0; cf < 4; ++cf)
          acc[s][cf] = __builtin_amdgcn_mfma_f32_16x16x32_bf16(bhv[cf], al[s], acc[s][cf], 0, 0, 0);
      __builtin_amdgcn_s_setprio(0);
    }
    __syncthreads();  // all waves done reading this layer's activations

    // In swapped layout: this lane's 16 outputs are for m-row = `row`,
    // n = wv*64 + cf*16 + kq*4 + j  (4 consecutive n per cf).
    if (L < 2) {
      const float* __restrict__ bias = (L == 0) ? b1 : b2;
#pragma unroll
      for (int cf = 0; cf < 4; ++cf) {
        const int n = (wv << 6) + (cf << 4) + (kq << 2);
        const float4 bv4 = *(const float4*)(bias + n);
        const float bvv[4] = {bv4.x, bv4.y, bv4.z, bv4.w};
        float v[NS][4];
#pragma unroll
        for (int j = 0; j < 4; ++j) {
          const float a0 = acc[0][cf][j] + bvv[j];
          const float e = __expf(2.f * a0);
          const float y = 1.f - __fdividef(2.f, e + 1.f);
          const float d = 1.f - y * y;
          const float a1 = acc[1][cf][j];
          const float o1 = d * a1;
          v[0][j] = y;
          v[1][j] = o1;
          if (NS == 5) {
            const float a2 = acc[2][cf][j];
            const float a3 = acc[3][cf][j];
            const float a4 = acc[4][cf][j];
            v[2][j] = fmaf(-2.f * y * a1, o1, d * a2);
            v[3][j] = d * a3;
            v[4][j] = fmaf(-2.f * y * v[3][j], a3, d * a4);
          }
        }
#pragma unroll
        for (int p = 0; p < NS; ++p) {
          union { unsigned u[2]; short4_t s4; } H, L4;
          split_pair(v[p][0], v[p][1], H.u[0], L4.u[0]);
          split_pair(v[p][2], v[p][3], H.u[1], L4.u[1]);
          *(short4_t*)&Ald[p][0][aoff(row, n)] = H.s4;
          *(short4_t*)&Ald[p][0][aoff(row, 512 + n)] = L4.s4;
        }
      }
      __syncthreads();
    } else {
      // ---- final layer: coupling + 512->1 dot + loss ----
      float s0 = 0.f, s1 = 0.f;
#pragma unroll
      for (int cf = 0; cf < 4; ++cf) {
        const int n = (wv << 6) + (cf << 4) + (kq << 2);
        const float4 bv4 = *(const float4*)(b3 + n);
        const float4 w44 = *(const float4*)(W4 + n);
        const float bvv[4] = {bv4.x, bv4.y, bv4.z, bv4.w};
        const float wvv[4] = {w44.x, w44.y, w44.z, w44.w};
#pragma unroll
        for (int j = 0; j < 4; ++j) {
          const float a0 = acc[0][cf][j] + bvv[j];
          const float e = __expf(2.f * a0);
          const float y = 1.f - __fdividef(2.f, e + 1.f);
          const float d = 1.f - y * y;
          const float a1 = acc[1][cf][j];
          const float o1 = d * a1;
          if (NS == 5) {
            const float a2 = acc[2][cf][j];
            const float a3 = acc[3][cf][j];
            const float a4 = acc[4][cf][j];
            const float o2 = fmaf(-2.f * y * a1, o1, d * a2);
            const float o3 = d * a3;
            const float o4 = fmaf(-2.f * y * o3, a3, d * a4);
            s0 = fmaf(o2, wvv[j], s0);   // u_tt partial for m-row `row`
            s1 = fmaf(o4, wvv[j], s1);   // u_xx partial
          } else {
            s0 = fmaf(y, wvv[j], s0);    // u partial
            s1 = fmaf(o1, wvv[j], s1);   // u_t partial
          }
        }
      }
      // reduce over the 4 kq-groups (lanes sharing m-row): flip bits 4,5
      s0 += __shfl_xor(s0, 16); s0 += __shfl_xor(s0, 32);
      s1 += __shfl_xor(s1, 16); s1 += __shfl_xor(s1, 32);
      // cross-wave reduce via LDS scratch (activations no longer needed)
      float* scr = (float*)&Ald[0][0][0];  // [2][8][16]
      if (lane < 16) {
        scr[(wv << 4) + lane] = s0;
        scr[128 + (wv << 4) + lane] = s1;
      }
      __syncthreads();
      if (tid < 16) {
        float q0 = 0.f, q1 = 0.f;
#pragma unroll
        for (int w = 0; w < 8; ++w) {
          q0 += scr[(w << 4) + tid];
          q1 += scr[128 + (w << 4) + tid];
        }
        if (NS == 5) {
          const float c0 = cc[0];
          const float pred = q0 - c0 * c0 * q1;
          const float r = pred - t0[rowbase + tid];
          float v = r * r;
#pragma unroll
          for (int off = 1; off < 16; off <<= 1) v += __shfl_xor(v, off);
          if (tid == 0) atomicAdd(out + 2, scale * v);
        } else {
          const float r0 = q0 + b4[0] - t0[rowbase + tid];
          const float r1 = q1 - t1[rowbase + tid];
          float v0 = r0 * r0, v1 = r1 * r1;
#pragma unroll
          for (int off = 1; off < 16; off <<= 1) {
            v0 += __shfl_xor(v0, off);
            v1 += __shfl_xor(v1, off);
          }
          if (tid == 0) {
            atomicAdd(out + 0, scale * v0);
            atomicAdd(out + 1, scale * v1);
          }
        }
      }
    }
  }
}

// ---------------------------------------------------------------------------
extern "C" void kernel_launch(void* const* d_in, const int* in_sizes, int n_in,
                              void* d_out, int out_size, void* d_ws, size_t ws_size,
                              hipStream_t stream)
{
  const float* xt_int  = (const float*)d_in[0];
  const float* f       = (const float*)d_in[1];
  const float* xt_init = (const float*)d_in[2];
  const float* g       = (const float*)d_in[3];
  const float* gd      = (const float*)d_in[4];
  const float* W0 = (const float*)d_in[5];
  const float* b0 = (const float*)d_in[6];
  const float* W1 = (const float*)d_in[7];
  const float* b1 = (const float*)d_in[8];
  const float* W2 = (const float*)d_in[9];
  const float* b2 = (const float*)d_in[10];
  const float* W3 = (const float*)d_in[11];
  const float* b3 = (const float*)d_in[12];
  const float* W4 = (const float*)d_in[13];
  const float* b4 = (const float*)d_in[14];
  const float* c  = (const float*)d_in[15];
  float* out = (float*)d_out;

  hipMemsetAsync(out, 0, 3 * sizeof(float), stream);

  unsigned short* Wt = (unsigned short*)d_ws;  // 6 planes = 3 MiB of ws

  wsplit<<<HID, HID, 0, stream>>>(W1, Wt + 0 * WT1, Wt + 1 * WT1);
  wsplit<<<HID, HID, 0, stream>>>(W2, Wt + 2 * WT1, Wt + 3 * WT1);
  wsplit<<<HID, HID, 0, stream>>>(W3, Wt + 4 * WT1, Wt + 5 * WT1);

  const float sc_f = 0.5f / (float)N_INT;
  const float sc_i = 0.5f / (float)N_INIT;

  fused_mlp<5><<<N_INT / 16, 512, 0, stream>>>(
      xt_int, W0, b0, Wt, b1, b2, b3, W4, b4, c, f, nullptr, out, sc_f);
  fused_mlp<2><<<N_INIT / 16, 512, 0, stream>>>(
      xt_init, W0, b0, Wt, b1, b2, b3, W4, b4, nullptr, g, gd, out, sc_i);
}

// Round 17
// 2528.907 us; speedup vs baseline: 1.1207x; 1.0038x over previous
//
#include <hip/hip_runtime.h>
#include <hip/hip_bf16.h>
#include <cstdint>
#include <cstddef>

#define HID 512
#define N_INT 131072
#define N_INIT 32768
#define WT1 ((size_t)HID * HID)

typedef __attribute__((ext_vector_type(8))) short short8_t;
typedef __attribute__((ext_vector_type(4))) short short4_t;
typedef __attribute__((ext_vector_type(4))) float floatx4;

__device__ __forceinline__ float bf2f(unsigned short u) {
  return __uint_as_float(((unsigned)u) << 16);
}
__device__ __forceinline__ unsigned short f2bf_rne(float x) {
  unsigned u = __float_as_uint(x);
  unsigned r = u + 0x7FFF + ((u >> 16) & 1);
  return (unsigned short)(r >> 16);
}
__device__ __forceinline__ void st_split(unsigned short* hi, unsigned short* lo,
                                         size_t off, float x) {
  unsigned short h = f2bf_rne(x);
  hi[off] = h;
  lo[off] = f2bf_rne(x - bf2f(h));
}

// Packed bf16 split of a float pair via HW cvt (RNE, same bits as f2bf_rne):
__device__ __forceinline__ void split_pair(float a, float b,
                                           unsigned& hi, unsigned& lo) {
  unsigned h;
  asm("v_cvt_pk_bf16_f32 %0, %1, %2" : "=v"(h) : "v"(a), "v"(b));
  const float ra = __uint_as_float(h << 16);
  const float rb = __uint_as_float(h & 0xffff0000u);
  unsigned l;
  asm("v_cvt_pk_bf16_f32 %0, %1, %2" : "=v"(l) : "v"(a - ra), "v"(b - rb));
  hi = h;
  lo = l;
}

// fast tanh via exp2-backed __expf (same formula the epilogues use)
__device__ __forceinline__ float tanh_fast(float a) {
  const float e = __expf(2.f * a);
  return 1.f - __fdividef(2.f, e + 1.f);
}

// ---------------------------------------------------------------------------
// W split + pack into B-fraglet layout (same as prior verified rounds):
//   fraglet (n>>4, k>>5); lane = ((k>>3)&3)*16 + (n&15); elem = k&7.
// ---------------------------------------------------------------------------
__global__ __launch_bounds__(512) void wsplit(
    const float* __restrict__ W,
    unsigned short* __restrict__ WfH, unsigned short* __restrict__ WfL)
{
  int n = blockIdx.x;
  int k = threadIdx.x;
  float w = W[(size_t)k * HID + n];
  size_t o = ((((size_t)(n >> 4) * 16 + (k >> 5)) * 64
               + ((k >> 3) & 3) * 16 + (n & 15)) << 3) + (k & 7);
  st_split(WfH, WfL, o, w);
}

// ---------------------------------------------------------------------------
// Fully fused MLP pass. Activations live in LDS as MFMA A-FRAGLETS:
//   stream s plane = [part hi/lo][ktile 0..15][lane 0..63][elem 0..7]
//   (k = ktile*32 + (lane>>4)*8 + elem, m-row = lane&15)
// -> k-loop A-read = base + lane*16B + static immediate: contiguous 1KB per
//    wave read, conflict-free (m136 baseline), zero address VALU.
// -> epilogue writes aligned b64 into contiguous 256B chunks (conflict-free).
// mfma(W_frag, Act_frag) swapped-operand: lane&15 = m-row, reg j = 4
// consecutive n (= next-layer k). Product terms & per-acc order (hh,hl,lh)
// identical to rounds 2-16 -> bit-identical GEMM numerics.
// Block = 16 rows x 512 cols, 512 thr (8 waves, each owns a 64-col slice).
// ---------------------------------------------------------------------------
template <int NS>
__global__ __launch_bounds__(512) void fused_mlp(
    const float* __restrict__ xt,
    const float* __restrict__ W0, const float* __restrict__ b0,
    const unsigned short* __restrict__ Wf,   // 6 planes: L1H,L1L,L2H,L2L,L3H,L3L
    const float* __restrict__ b1, const float* __restrict__ b2,
    const float* __restrict__ b3,
    const float* __restrict__ W4, const float* __restrict__ b4,
    const float* __restrict__ cc,            // c (interior), unused for init
    const float* __restrict__ t0,            // f (interior) or g (init)
    const float* __restrict__ t1,            // unused or gd (init)
    float* __restrict__ out, float scale)
{
  // per stream: hi 8192 ushorts + lo 8192 = 16384 (32KB). NS=5 -> 160KB.
  __shared__ unsigned short Ald[NS * 16384];

  const int tid = threadIdx.x;
  const long rowbase = (long)blockIdx.x * 16;
  const int lane = tid & 63;
  const int wv = tid >> 6;        // 0..7: 64-col slice
  const int row = lane & 15;      // m-row
  const int kq = lane >> 4;       // k-quarter

  // ---- layer 0: closed-form tangents straight into LDS fraglets ----
  {
    const int r0 = tid & 15;
    const int cg = tid >> 4;  // 0..31, 16 cols each
    const long gr = rowbase + r0;
    const float x = xt[gr * 2 + 0];
    const float tv = xt[gr * 2 + 1];
#pragma unroll
    for (int sc = 0; sc < 2; ++sc) {
      const int j0 = cg * 16 + sc * 8;
      float v[NS][8];
#pragma unroll
      for (int jj = 0; jj < 8; ++jj) {
        const float wx = W0[j0 + jj];
        const float wt = W0[HID + j0 + jj];
        const float a = fmaf(x, wx, fmaf(tv, wt, b0[j0 + jj]));
        const float y = tanh_fast(a);
        const float d = 1.f - y * y;
        v[0][jj] = y;
        v[1][jj] = d * wt;
        if (NS == 5) {
          v[2][jj] = -2.f * y * d * wt * wt;
          v[3][jj] = d * wx;
          v[4][jj] = -2.f * y * d * wx * wx;
        }
      }
      // fraglet target: ktile = j0>>5, lane' = ((j0>>3)&3)*16 + r0, elem 0..7
      const int di = ((j0 >> 5) << 9) + ((((j0 >> 3) & 3) * 16 + r0) << 3);
#pragma unroll
      for (int p = 0; p < NS; ++p) {
        union { unsigned u[4]; short8_t s8; } H, L;
#pragma unroll
        for (int q = 0; q < 4; ++q)
          split_pair(v[p][2 * q], v[p][2 * q + 1], H.u[q], L.u[q]);
        *(short8_t*)&Ald[p * 16384 + di] = H.s8;
        *(short8_t*)&Ald[p * 16384 + 8192 + di] = L.s8;
      }
    }
  }
  __syncthreads();

  // per-stream A-fraglet base pointers (LDS base fixed across layers)
  const unsigned short* pA[NS];
#pragma unroll
  for (int s = 0; s < NS; ++s) pA[s] = &Ald[s * 16384 + (lane << 3)];

  for (int L = 0; L < 3; ++L) {
    const unsigned short* __restrict__ WH = Wf + (size_t)L * 2 * WT1;
    const unsigned short* __restrict__ WL2 = WH + WT1;

    floatx4 acc[NS][4];
#pragma unroll
    for (int s = 0; s < NS; ++s)
#pragma unroll
      for (int cf = 0; cf < 4; ++cf)
#pragma unroll
        for (int e = 0; e < 4; ++e) acc[s][cf][e] = 0.f;

#pragma unroll 4
    for (int t = 0; t < 16; ++t) {
      short8_t ah[NS], al[NS], bhv[4], blv[4];
#pragma unroll
      for (int s = 0; s < NS; ++s) {
        ah[s] = *(const short8_t*)(pA[s] + (t << 9));          // hi, imm offset
        al[s] = *(const short8_t*)(pA[s] + 8192 + (t << 9));   // lo, imm offset
      }
#pragma unroll
      for (int cf = 0; cf < 4; ++cf) {
        const size_t bo = (((size_t)((wv * 4 + cf) * 16 + t)) << 9) + (lane << 3);
        bhv[cf] = *(const short8_t*)(WH + bo);
        blv[cf] = *(const short8_t*)(WL2 + bo);
      }
      __builtin_amdgcn_s_setprio(1);
#pragma unroll
      for (int s = 0; s < NS; ++s)
#pragma unroll
        for (int cf = 0; cf < 4; ++cf)
          acc[s][cf] = __builtin_amdgcn_mfma_f32_16x16x32_bf16(bhv[cf], ah[s], acc[s][cf], 0, 0, 0);
#pragma unroll
      for (int s = 0; s < NS; ++s)
#pragma unroll
        for (int cf = 0; cf < 4; ++cf)
          acc[s][cf] = __builtin_amdgcn_mfma_f32_16x16x32_bf16(blv[cf], ah[s], acc[s][cf], 0, 0, 0);
#pragma unroll
      for (int s = 0; s < NS; ++s)
#pragma unroll
        for (int cf = 0; cf < 4; ++cf)
          acc[s][cf] = __builtin_amdgcn_mfma_f32_16x16x32_bf16(bhv[cf], al[s], acc[s][cf], 0, 0, 0);
      __builtin_amdgcn_s_setprio(0);
    }
    __syncthreads();  // all waves done reading this layer's activations

    // lane's 16 outputs: m-row = `row`, n = wv*64 + cf*16 + kq*4 + j.
    if (L < 2) {
      const float* __restrict__ bias = (L == 0) ? b1 : b2;
#pragma unroll
      for (int cf = 0; cf < 4; ++cf) {
        const int n = (wv << 6) + (cf << 4) + (kq << 2);
        const float4 bv4 = *(const float4*)(bias + n);
        const float bvv[4] = {bv4.x, bv4.y, bv4.z, bv4.w};
        float v[NS][4];
#pragma unroll
        for (int j = 0; j < 4; ++j) {
          const float a0 = acc[0][cf][j] + bvv[j];
          const float y = tanh_fast(a0);
          const float d = 1.f - y * y;
          const float a1 = acc[1][cf][j];
          const float o1 = d * a1;
          v[0][j] = y;
          v[1][j] = o1;
          if (NS == 5) {
            const float a2 = acc[2][cf][j];
            const float a3 = acc[3][cf][j];
            const float a4 = acc[4][cf][j];
            v[2][j] = fmaf(-2.f * y * a1, o1, d * a2);
            v[3][j] = d * a3;
            v[4][j] = fmaf(-2.f * y * v[3][j], a3, d * a4);
          }
        }
        // fraglet write: ktile = n>>5, lane' = (((n>>3)&3))*16 + row,
        // elem base = n&7 (= (kq&1)*4), 4 consecutive -> aligned b64.
        const int di = ((n >> 5) << 9) + ((((n >> 3) & 3) * 16 + row) << 3) + (n & 7);
#pragma unroll
        for (int p = 0; p < NS; ++p) {
          union { unsigned u[2]; short4_t s4; } H, L4;
          split_pair(v[p][0], v[p][1], H.u[0], L4.u[0]);
          split_pair(v[p][2], v[p][3], H.u[1], L4.u[1]);
          *(short4_t*)&Ald[p * 16384 + di] = H.s4;
          *(short4_t*)&Ald[p * 16384 + 8192 + di] = L4.s4;
        }
      }
      __syncthreads();
    } else {
      // ---- final layer: coupling + 512->1 dot + loss ----
      float s0 = 0.f, s1 = 0.f;
#pragma unroll
      for (int cf = 0; cf < 4; ++cf) {
        const int n = (wv << 6) + (cf << 4) + (kq << 2);
        const float4 bv4 = *(const float4*)(b3 + n);
        const float4 w44 = *(const float4*)(W4 + n);
        const float bvv[4] = {bv4.x, bv4.y, bv4.z, bv4.w};
        const float wvv[4] = {w44.x, w44.y, w44.z, w44.w};
#pragma unroll
        for (int j = 0; j < 4; ++j) {
          const float a0 = acc[0][cf][j] + bvv[j];
          const float y = tanh_fast(a0);
          const float d = 1.f - y * y;
          const float a1 = acc[1][cf][j];
          const float o1 = d * a1;
          if (NS == 5) {
            const float a2 = acc[2][cf][j];
            const float a3 = acc[3][cf][j];
            const float a4 = acc[4][cf][j];
            const float o2 = fmaf(-2.f * y * a1, o1, d * a2);
            const float o3 = d * a3;
            const float o4 = fmaf(-2.f * y * o3, a3, d * a4);
            s0 = fmaf(o2, wvv[j], s0);   // u_tt partial for m-row `row`
            s1 = fmaf(o4, wvv[j], s1);   // u_xx partial
          } else {
            s0 = fmaf(y, wvv[j], s0);    // u partial
            s1 = fmaf(o1, wvv[j], s1);   // u_t partial
          }
        }
      }
      // reduce over the 4 kq-groups (lanes sharing m-row): flip bits 4,5
      s0 += __shfl_xor(s0, 16); s0 += __shfl_xor(s0, 32);
      s1 += __shfl_xor(s1, 16); s1 += __shfl_xor(s1, 32);
      // cross-wave reduce via LDS scratch (activations no longer needed)
      float* scr = (float*)&Ald[0];  // [2][8][16]
      if (lane < 16) {
        scr[(wv << 4) + lane] = s0;
        scr[128 + (wv << 4) + lane] = s1;
      }
      __syncthreads();
      if (tid < 16) {
        float q0 = 0.f, q1 = 0.f;
#pragma unroll
        for (int w = 0; w < 8; ++w) {
          q0 += scr[(w << 4) + tid];
          q1 += scr[128 + (w << 4) + tid];
        }
        if (NS == 5) {
          const float c0 = cc[0];
          const float pred = q0 - c0 * c0 * q1;
          const float r = pred - t0[rowbase + tid];
          float v = r * r;
#pragma unroll
          for (int off = 1; off < 16; off <<= 1) v += __shfl_xor(v, off);
          if (tid == 0) atomicAdd(out + 2, scale * v);
        } else {
          const float r0 = q0 + b4[0] - t0[rowbase + tid];
          const float r1 = q1 - t1[rowbase + tid];
          float v0 = r0 * r0, v1 = r1 * r1;
#pragma unroll
          for (int off = 1; off < 16; off <<= 1) {
            v0 += __shfl_xor(v0, off);
            v1 += __shfl_xor(v1, off);
          }
          if (tid == 0) {
            atomicAdd(out + 0, scale * v0);
            atomicAdd(out + 1, scale * v1);
          }
        }
      }
    }
  }
}

// ---------------------------------------------------------------------------
extern "C" void kernel_launch(void* const* d_in, const int* in_sizes, int n_in,
                              void* d_out, int out_size, void* d_ws, size_t ws_size,
                              hipStream_t stream)
{
  const float* xt_int  = (const float*)d_in[0];
  const float* f       = (const float*)d_in[1];
  const float* xt_init = (const float*)d_in[2];
  const float* g       = (const float*)d_in[3];
  const float* gd      = (const float*)d_in[4];
  const float* W0 = (const float*)d_in[5];
  const float* b0 = (const float*)d_in[6];
  const float* W1 = (const float*)d_in[7];
  const float* b1 = (const float*)d_in[8];
  const float* W2 = (const float*)d_in[9];
  const float* b2 = (const float*)d_in[10];
  const float* W3 = (const float*)d_in[11];
  const float* b3 = (const float*)d_in[12];
  const float* W4 = (const float*)d_in[13];
  const float* b4 = (const float*)d_in[14];
  const float* c  = (const float*)d_in[15];
  float* out = (float*)d_out;

  hipMemsetAsync(out, 0, 3 * sizeof(float), stream);

  unsigned short* Wt = (unsigned short*)d_ws;  // 6 planes = 3 MiB of ws

  wsplit<<<HID, HID, 0, stream>>>(W1, Wt + 0 * WT1, Wt + 1 * WT1);
  wsplit<<<HID, HID, 0, stream>>>(W2, Wt + 2 * WT1, Wt + 3 * WT1);
  wsplit<<<HID, HID, 0, stream>>>(W3, Wt + 4 * WT1, Wt + 5 * WT1);

  const float sc_f = 0.5f / (float)N_INT;
  const float sc_i = 0.5f / (float)N_INIT;

  fused_mlp<5><<<N_INT / 16, 512, 0, stream>>>(
      xt_int, W0, b0, Wt, b1, b2, b3, W4, b4, c, f, nullptr, out, sc_f);
  fused_mlp<2><<<N_INIT / 16, 512, 0, stream>>>(
      xt_init, W0, b0, Wt, b1, b2, b3, W4, b4, nullptr, g, gd, out, sc_i);
}

// Round 18
// 2500.211 us; speedup vs baseline: 1.1336x; 1.0115x over previous
//
#include <hip/hip_runtime.h>
#include <hip/hip_bf16.h>
#include <cstdint>
#include <cstddef>

#define HID 512
#define N_INT 131072
#define N_INIT 32768
#define WT1 ((size_t)HID * HID)

typedef __attribute__((ext_vector_type(8))) short short8_t;
typedef __attribute__((ext_vector_type(4))) short short4_t;
typedef __attribute__((ext_vector_type(4))) float floatx4;

__device__ __forceinline__ float bf2f(unsigned short u) {
  return __uint_as_float(((unsigned)u) << 16);
}
__device__ __forceinline__ unsigned short f2bf_rne(float x) {
  unsigned u = __float_as_uint(x);
  unsigned r = u + 0x7FFF + ((u >> 16) & 1);
  return (unsigned short)(r >> 16);
}
__device__ __forceinline__ void st_split(unsigned short* hi, unsigned short* lo,
                                         size_t off, float x) {
  unsigned short h = f2bf_rne(x);
  hi[off] = h;
  lo[off] = f2bf_rne(x - bf2f(h));
}

// Packed bf16 split of a float pair via HW cvt (RNE, same bits as f2bf_rne):
__device__ __forceinline__ void split_pair(float a, float b,
                                           unsigned& hi, unsigned& lo) {
  unsigned h;
  asm("v_cvt_pk_bf16_f32 %0, %1, %2" : "=v"(h) : "v"(a), "v"(b));
  const float ra = __uint_as_float(h << 16);
  const float rb = __uint_as_float(h & 0xffff0000u);
  unsigned l;
  asm("v_cvt_pk_bf16_f32 %0, %1, %2" : "=v"(l) : "v"(a - ra), "v"(b - rb));
  hi = h;
  lo = l;
}

// fast tanh via exp2-backed __expf (same formula the epilogues use)
__device__ __forceinline__ float tanh_fast(float a) {
  const float e = __expf(2.f * a);
  return 1.f - __fdividef(2.f, e + 1.f);
}

// ---------------------------------------------------------------------------
// W split + pack into B-fraglet layout (same as prior verified rounds):
//   fraglet (n>>4, k>>5); lane = ((k>>3)&3)*16 + (n&15); elem = k&7.
// ---------------------------------------------------------------------------
__global__ __launch_bounds__(512) void wsplit(
    const float* __restrict__ W,
    unsigned short* __restrict__ WfH, unsigned short* __restrict__ WfL)
{
  int n = blockIdx.x;
  int k = threadIdx.x;
  float w = W[(size_t)k * HID + n];
  size_t o = ((((size_t)(n >> 4) * 16 + (k >> 5)) * 64
               + ((k >> 3) & 3) * 16 + (n & 15)) << 3) + (k & 7);
  st_split(WfH, WfL, o, w);
}

// ---------------------------------------------------------------------------
// Fully fused MLP pass. Activations in LDS as MFMA A-fraglets (r17 layout,
// conflict-free, zero address VALU). NEW: waves that share a SIMD (wv and
// wv+4) walk the k-tiles with an 8-tile phase offset (tt = t + (wv>>2)*8
// mod 16) -> their B-load-wait and MFMA-burst phases interleave instead of
// coinciding, so L2 latency hides under the partner wave's compute.
// (k-accumulation reorder only: result differs at ~ulp level, far below
// the 3.4e-4 threshold.) All else identical to round 17.
// ---------------------------------------------------------------------------
template <int NS>
__global__ __launch_bounds__(512) void fused_mlp(
    const float* __restrict__ xt,
    const float* __restrict__ W0, const float* __restrict__ b0,
    const unsigned short* __restrict__ Wf,   // 6 planes: L1H,L1L,L2H,L2L,L3H,L3L
    const float* __restrict__ b1, const float* __restrict__ b2,
    const float* __restrict__ b3,
    const float* __restrict__ W4, const float* __restrict__ b4,
    const float* __restrict__ cc,            // c (interior), unused for init
    const float* __restrict__ t0,            // f (interior) or g (init)
    const float* __restrict__ t1,            // unused or gd (init)
    float* __restrict__ out, float scale)
{
  // per stream: hi 8192 ushorts + lo 8192 = 16384 (32KB). NS=5 -> 160KB.
  __shared__ unsigned short Ald[NS * 16384];

  const int tid = threadIdx.x;
  const long rowbase = (long)blockIdx.x * 16;
  const int lane = tid & 63;
  const int wv = tid >> 6;        // 0..7: 64-col slice
  const int row = lane & 15;      // m-row
  const int kq = lane >> 4;       // k-quarter
  const int tofs = (wv >> 2) << 3;  // 0 for waves 0-3, 8 for waves 4-7

  // ---- layer 0: closed-form tangents straight into LDS fraglets ----
  {
    const int r0 = tid & 15;
    const int cg = tid >> 4;  // 0..31, 16 cols each
    const long gr = rowbase + r0;
    const float x = xt[gr * 2 + 0];
    const float tv = xt[gr * 2 + 1];
#pragma unroll
    for (int sc = 0; sc < 2; ++sc) {
      const int j0 = cg * 16 + sc * 8;
      float v[NS][8];
#pragma unroll
      for (int jj = 0; jj < 8; ++jj) {
        const float wx = W0[j0 + jj];
        const float wt = W0[HID + j0 + jj];
        const float a = fmaf(x, wx, fmaf(tv, wt, b0[j0 + jj]));
        const float y = tanh_fast(a);
        const float d = 1.f - y * y;
        v[0][jj] = y;
        v[1][jj] = d * wt;
        if (NS == 5) {
          v[2][jj] = -2.f * y * d * wt * wt;
          v[3][jj] = d * wx;
          v[4][jj] = -2.f * y * d * wx * wx;
        }
      }
      // fraglet target: ktile = j0>>5, lane' = ((j0>>3)&3)*16 + r0, elem 0..7
      const int di = ((j0 >> 5) << 9) + ((((j0 >> 3) & 3) * 16 + r0) << 3);
#pragma unroll
      for (int p = 0; p < NS; ++p) {
        union { unsigned u[4]; short8_t s8; } H, L;
#pragma unroll
        for (int q = 0; q < 4; ++q)
          split_pair(v[p][2 * q], v[p][2 * q + 1], H.u[q], L.u[q]);
        *(short8_t*)&Ald[p * 16384 + di] = H.s8;
        *(short8_t*)&Ald[p * 16384 + 8192 + di] = L.s8;
      }
    }
  }
  __syncthreads();

  // per-stream A-fraglet base pointers (LDS base fixed across layers)
  const unsigned short* pA[NS];
#pragma unroll
  for (int s = 0; s < NS; ++s) pA[s] = &Ald[s * 16384 + (lane << 3)];

  for (int L = 0; L < 3; ++L) {
    const unsigned short* __restrict__ WH = Wf + (size_t)L * 2 * WT1;
    const unsigned short* __restrict__ WL2 = WH + WT1;

    floatx4 acc[NS][4];
#pragma unroll
    for (int s = 0; s < NS; ++s)
#pragma unroll
      for (int cf = 0; cf < 4; ++cf)
#pragma unroll
        for (int e = 0; e < 4; ++e) acc[s][cf][e] = 0.f;

#pragma unroll 4
    for (int t = 0; t < 16; ++t) {
      const int tt = (t + tofs) & 15;   // SIMD-partner waves are 8 tiles apart
      short8_t ah[NS], al[NS], bhv[4], blv[4];
#pragma unroll
      for (int s = 0; s < NS; ++s) {
        ah[s] = *(const short8_t*)(pA[s] + (tt << 9));          // hi
        al[s] = *(const short8_t*)(pA[s] + 8192 + (tt << 9));   // lo
      }
#pragma unroll
      for (int cf = 0; cf < 4; ++cf) {
        const size_t bo = (((size_t)((wv * 4 + cf) * 16 + tt)) << 9) + (lane << 3);
        bhv[cf] = *(const short8_t*)(WH + bo);
        blv[cf] = *(const short8_t*)(WL2 + bo);
      }
      __builtin_amdgcn_s_setprio(1);
#pragma unroll
      for (int s = 0; s < NS; ++s)
#pragma unroll
        for (int cf = 0; cf < 4; ++cf)
          acc[s][cf] = __builtin_amdgcn_mfma_f32_16x16x32_bf16(bhv[cf], ah[s], acc[s][cf], 0, 0, 0);
#pragma unroll
      for (int s = 0; s < NS; ++s)
#pragma unroll
        for (int cf = 0; cf < 4; ++cf)
          acc[s][cf] = __builtin_amdgcn_mfma_f32_16x16x32_bf16(blv[cf], ah[s], acc[s][cf], 0, 0, 0);
#pragma unroll
      for (int s = 0; s < NS; ++s)
#pragma unroll
        for (int cf = 0; cf < 4; ++cf)
          acc[s][cf] = __builtin_amdgcn_mfma_f32_16x16x32_bf16(bhv[cf], al[s], acc[s][cf], 0, 0, 0);
      __builtin_amdgcn_s_setprio(0);
    }
    __syncthreads();  // all waves done reading this layer's activations

    // lane's 16 outputs: m-row = `row`, n = wv*64 + cf*16 + kq*4 + j.
    if (L < 2) {
      const float* __restrict__ bias = (L == 0) ? b1 : b2;
#pragma unroll
      for (int cf = 0; cf < 4; ++cf) {
        const int n = (wv << 6) + (cf << 4) + (kq << 2);
        const float4 bv4 = *(const float4*)(bias + n);
        const float bvv[4] = {bv4.x, bv4.y, bv4.z, bv4.w};
        float v[NS][4];
#pragma unroll
        for (int j = 0; j < 4; ++j) {
          const float a0 = acc[0][cf][j] + bvv[j];
          const float y = tanh_fast(a0);
          const float d = 1.f - y * y;
          const float a1 = acc[1][cf][j];
          const float o1 = d * a1;
          v[0][j] = y;
          v[1][j] = o1;
          if (NS == 5) {
            const float a2 = acc[2][cf][j];
            const float a3 = acc[3][cf][j];
            const float a4 = acc[4][cf][j];
            v[2][j] = fmaf(-2.f * y * a1, o1, d * a2);
            v[3][j] = d * a3;
            v[4][j] = fmaf(-2.f * y * v[3][j], a3, d * a4);
          }
        }
        // fraglet write: ktile = n>>5, lane' = (((n>>3)&3))*16 + row,
        // elem base = n&7, 4 consecutive -> aligned b64.
        const int di = ((n >> 5) << 9) + ((((n >> 3) & 3) * 16 + row) << 3) + (n & 7);
#pragma unroll
        for (int p = 0; p < NS; ++p) {
          union { unsigned u[2]; short4_t s4; } H, L4;
          split_pair(v[p][0], v[p][1], H.u[0], L4.u[0]);
          split_pair(v[p][2], v[p][3], H.u[1], L4.u[1]);
          *(short4_t*)&Ald[p * 16384 + di] = H.s4;
          *(short4_t*)&Ald[p * 16384 + 8192 + di] = L4.s4;
        }
      }
      __syncthreads();
    } else {
      // ---- final layer: coupling + 512->1 dot + loss ----
      float s0 = 0.f, s1 = 0.f;
#pragma unroll
      for (int cf = 0; cf < 4; ++cf) {
        const int n = (wv << 6) + (cf << 4) + (kq << 2);
        const float4 bv4 = *(const float4*)(b3 + n);
        const float4 w44 = *(const float4*)(W4 + n);
        const float bvv[4] = {bv4.x, bv4.y, bv4.z, bv4.w};
        const float wvv[4] = {w44.x, w44.y, w44.z, w44.w};
#pragma unroll
        for (int j = 0; j < 4; ++j) {
          const float a0 = acc[0][cf][j] + bvv[j];
          const float y = tanh_fast(a0);
          const float d = 1.f - y * y;
          const float a1 = acc[1][cf][j];
          const float o1 = d * a1;
          if (NS == 5) {
            const float a2 = acc[2][cf][j];
            const float a3 = acc[3][cf][j];
            const float a4 = acc[4][cf][j];
            const float o2 = fmaf(-2.f * y * a1, o1, d * a2);
            const float o3 = d * a3;
            const float o4 = fmaf(-2.f * y * o3, a3, d * a4);
            s0 = fmaf(o2, wvv[j], s0);   // u_tt partial for m-row `row`
            s1 = fmaf(o4, wvv[j], s1);   // u_xx partial
          } else {
            s0 = fmaf(y, wvv[j], s0);    // u partial
            s1 = fmaf(o1, wvv[j], s1);   // u_t partial
          }
        }
      }
      // reduce over the 4 kq-groups (lanes sharing m-row): flip bits 4,5
      s0 += __shfl_xor(s0, 16); s0 += __shfl_xor(s0, 32);
      s1 += __shfl_xor(s1, 16); s1 += __shfl_xor(s1, 32);
      // cross-wave reduce via LDS scratch (activations no longer needed)
      float* scr = (float*)&Ald[0];  // [2][8][16]
      if (lane < 16) {
        scr[(wv << 4) + lane] = s0;
        scr[128 + (wv << 4) + lane] = s1;
      }
      __syncthreads();
      if (tid < 16) {
        float q0 = 0.f, q1 = 0.f;
#pragma unroll
        for (int w = 0; w < 8; ++w) {
          q0 += scr[(w << 4) + tid];
          q1 += scr[128 + (w << 4) + tid];
        }
        if (NS == 5) {
          const float c0 = cc[0];
          const float pred = q0 - c0 * c0 * q1;
          const float r = pred - t0[rowbase + tid];
          float v = r * r;
#pragma unroll
          for (int off = 1; off < 16; off <<= 1) v += __shfl_xor(v, off);
          if (tid == 0) atomicAdd(out + 2, scale * v);
        } else {
          const float r0 = q0 + b4[0] - t0[rowbase + tid];
          const float r1 = q1 - t1[rowbase + tid];
          float v0 = r0 * r0, v1 = r1 * r1;
#pragma unroll
          for (int off = 1; off < 16; off <<= 1) {
            v0 += __shfl_xor(v0, off);
            v1 += __shfl_xor(v1, off);
          }
          if (tid == 0) {
            atomicAdd(out + 0, scale * v0);
            atomicAdd(out + 1, scale * v1);
          }
        }
      }
    }
  }
}

// ---------------------------------------------------------------------------
extern "C" void kernel_launch(void* const* d_in, const int* in_sizes, int n_in,
                              void* d_out, int out_size, void* d_ws, size_t ws_size,
                              hipStream_t stream)
{
  const float* xt_int  = (const float*)d_in[0];
  const float* f       = (const float*)d_in[1];
  const float* xt_init = (const float*)d_in[2];
  const float* g       = (const float*)d_in[3];
  const float* gd      = (const float*)d_in[4];
  const float* W0 = (const float*)d_in[5];
  const float* b0 = (const float*)d_in[6];
  const float* W1 = (const float*)d_in[7];
  const float* b1 = (const float*)d_in[8];
  const float* W2 = (const float*)d_in[9];
  const float* b2 = (const float*)d_in[10];
  const float* W3 = (const float*)d_in[11];
  const float* b3 = (const float*)d_in[12];
  const float* W4 = (const float*)d_in[13];
  const float* b4 = (const float*)d_in[14];
  const float* c  = (const float*)d_in[15];
  float* out = (float*)d_out;

  hipMemsetAsync(out, 0, 3 * sizeof(float), stream);

  unsigned short* Wt = (unsigned short*)d_ws;  // 6 planes = 3 MiB of ws

  wsplit<<<HID, HID, 0, stream>>>(W1, Wt + 0 * WT1, Wt + 1 * WT1);
  wsplit<<<HID, HID, 0, stream>>>(W2, Wt + 2 * WT1, Wt + 3 * WT1);
  wsplit<<<HID, HID, 0, stream>>>(W3, Wt + 4 * WT1, Wt + 5 * WT1);

  const float sc_f = 0.5f / (float)N_INT;
  const float sc_i = 0.5f / (float)N_INIT;

  fused_mlp<5><<<N_INT / 16, 512, 0, stream>>>(
      xt_int, W0, b0, Wt, b1, b2, b3, W4, b4, c, f, nullptr, out, sc_f);
  fused_mlp<2><<<N_INIT / 16, 512, 0, stream>>>(
      xt_init, W0, b0, Wt, b1, b2, b3, W4, b4, nullptr, g, gd, out, sc_i);
}